// Round 1
// baseline (147.258 us; speedup 1.0000x reference)
//
#include <hip/hip_runtime.h>
#include <hip/hip_cooperative_groups.h>
#include <math.h>

namespace cg = cooperative_groups;

#define D 768
#define T 128
#define KC 16            // split-K chunks for GEMM1
#define CHUNKK (D / KC)  // 48
#define NSUB (CHUNKK / 16) // 3 sub-chunks of 16

// ln(0.9*0.99) = ln(0.891)
#define LN_ETA_DECAY (-0.11541085151132775f)

// ---------------------------------------------------------------------------
// Single cooperative kernel, 192 blocks x 256 threads, 3 phases:
//   P1: split-K partial GEMM  P = keys @ W^T     (was k1, 192 blocks)
//   P2: errW = sum_kc Ppart - values             (was k15, now spread 192 blocks)
//   P3: GEMM2 + fused W/mW/b/losses epilogue     (was k2, 144 of 192 blocks)
// grid.sync() between phases replaces two kernel-launch round-trips.
// LDS: phase-1 and phase-3 tiles overlaid in a union (66 KB) -> all 192
// blocks trivially co-resident (1 block/CU).
// ---------------------------------------------------------------------------

union SharedU {
    struct {
        float sKt[16][132];  // [k][t], pitch 132
        float sWo[16][68];   // [k][o], pitch 68
    } p1;
    struct {
        float sErr[T][64];   // errW[t, o-local]
        float sKs[T][64];    // 2*c[t]*keys[t, i-local]
        float sC[T];         // c[t]
        float sB0[64];       // bparam[o-local]
    } p3;
};

__global__ __launch_bounds__(256) void fused_all(
    const float* __restrict__ W,
    const float* __restrict__ keys,
    const float* __restrict__ values,
    const float* __restrict__ mW,
    const float* __restrict__ bparam,
    const float* __restrict__ mb,
    float* __restrict__ W_new,
    float* __restrict__ b_new,
    float* __restrict__ mW_new,
    float* __restrict__ mb_new,
    float* __restrict__ losses,
    float* __restrict__ Ppart,
    float* __restrict__ errW,
    float pow_eta_T, float beta_total, float Csum)
{
    __shared__ SharedU sh;
    cg::grid_group grid = cg::this_grid();

    const int b = blockIdx.x;
    const int tid = threadIdx.x;

    // =====================================================================
    // Phase 1: split-K partial GEMM (all 192 blocks)
    // bx = o-tile (0..11), by = k-chunk (0..15)
    // =====================================================================
    {
        float (&sKt)[16][132] = sh.p1.sKt;
        float (&sWo)[16][68]  = sh.p1.sWo;

        const int bx = b / KC;          // 0..11
        const int by = b % KC;          // 0..15
        const int obase = bx * 64;
        const int kbase = by * CHUNKK;
        const int ty = tid >> 4;   // t-group (8 t's)
        const int tx = tid & 15;   // o-group (4 o's)
        const int t0 = tid >> 2;   // staging row (0..63)
        const int q0 = tid & 3;    // staging float4-col (0..3)

        if (b == 0 && tid < T) losses[tid] = 0.f;

        float acc[8][4];
        #pragma unroll
        for (int j = 0; j < 8; ++j)
            #pragma unroll
            for (int n = 0; n < 4; ++n) acc[j][n] = 0.f;

        // prologue: load sub-chunk 0 into regs
        float4 gk0 = *reinterpret_cast<const float4*>(keys + t0 * D + kbase + q0 * 4);
        float4 gk1 = *reinterpret_cast<const float4*>(keys + (t0 + 64) * D + kbase + q0 * 4);
        float4 gw  = *reinterpret_cast<const float4*>(W + (obase + t0) * D + kbase + q0 * 4);

        for (int c = 0; c < NSUB; ++c) {
            // regs -> LDS (transposed to k-major)
            sKt[q0 * 4 + 0][t0] = gk0.x;
            sKt[q0 * 4 + 1][t0] = gk0.y;
            sKt[q0 * 4 + 2][t0] = gk0.z;
            sKt[q0 * 4 + 3][t0] = gk0.w;
            sKt[q0 * 4 + 0][t0 + 64] = gk1.x;
            sKt[q0 * 4 + 1][t0 + 64] = gk1.y;
            sKt[q0 * 4 + 2][t0 + 64] = gk1.z;
            sKt[q0 * 4 + 3][t0 + 64] = gk1.w;
            sWo[q0 * 4 + 0][t0] = gw.x;
            sWo[q0 * 4 + 1][t0] = gw.y;
            sWo[q0 * 4 + 2][t0] = gw.z;
            sWo[q0 * 4 + 3][t0] = gw.w;
            __syncthreads();

            // issue NEXT sub-chunk's loads (consumed at next iteration's store)
            if (c + 1 < NSUB) {
                const int kb = kbase + (c + 1) * 16;
                gk0 = *reinterpret_cast<const float4*>(keys + t0 * D + kb + q0 * 4);
                gk1 = *reinterpret_cast<const float4*>(keys + (t0 + 64) * D + kb + q0 * 4);
                gw  = *reinterpret_cast<const float4*>(W + (obase + t0) * D + kb + q0 * 4);
            }

            #pragma unroll
            for (int k = 0; k < 16; ++k) {
                float4 a0 = *reinterpret_cast<const float4*>(&sKt[k][ty * 8]);
                float4 a1 = *reinterpret_cast<const float4*>(&sKt[k][ty * 8 + 4]);
                float4 bb = *reinterpret_cast<const float4*>(&sWo[k][tx * 4]);
                const float av[8] = { a0.x, a0.y, a0.z, a0.w, a1.x, a1.y, a1.z, a1.w };
                const float bv[4] = { bb.x, bb.y, bb.z, bb.w };
                #pragma unroll
                for (int j = 0; j < 8; ++j)
                    #pragma unroll
                    for (int n = 0; n < 4; ++n) acc[j][n] += av[j] * bv[n];
            }
            __syncthreads();
        }

        float* outp = Ppart + by * (T * D);
        #pragma unroll
        for (int j = 0; j < 8; ++j) {
            const int t = ty * 8 + j;
            float4 v = { acc[j][0], acc[j][1], acc[j][2], acc[j][3] };
            *reinterpret_cast<float4*>(outp + t * D + obase + tx * 4) = v;
        }
    }

    grid.sync();

    // =====================================================================
    // Phase 2: errW = sum_kc Ppart[kc] - values  (spread over all 192 blocks,
    // threads 0..127 each handle one float4: 192*128 = 24576 = 128*768/4)
    // =====================================================================
    if (tid < 128) {
        const int fidx = b * 128 + tid;       // float4 index
        const int off = fidx * 4;             // float offset (= t*D + c, linear)
        float4 vv = *reinterpret_cast<const float4*>(values + off);
        float4 s = { -vv.x, -vv.y, -vv.z, -vv.w };
        #pragma unroll
        for (int kc = 0; kc < KC; ++kc) {
            float4 v = *reinterpret_cast<const float4*>(Ppart + kc * (T * D) + off);
            s.x += v.x; s.y += v.y; s.z += v.z; s.w += v.w;
        }
        *reinterpret_cast<float4*>(errW + off) = s;
    }

    grid.sync();

    // =====================================================================
    // Phase 3: GEMM2 G = errW^T @ (2c*keys) + fused epilogue (144 blocks)
    // =====================================================================
    if (b < 144) {
        float (&sErr)[T][64] = sh.p3.sErr;
        float (&sKs)[T][64]  = sh.p3.sKs;
        float (&sC)[T]       = sh.p3.sC;
        float (&sB0)[64]     = sh.p3.sB0;

        const int oT = b / 12, iT = b % 12;
        const int obase = oT * 64, ibase = iT * 64;
        const int ty = tid >> 4, tx = tid & 15;   // o-group, i-group

        // ---- epilogue prefetch: issue mW/W loads NOW, consume after GEMM2 ----
        float4 pm[4], pw[4];
        #pragma unroll
        for (int aa = 0; aa < 4; ++aa) {
            const int o = obase + ty * 4 + aa;
            const int i = ibase + tx * 4;
            pm[aa] = *reinterpret_cast<const float4*>(mW + o * D + i);
            pw[aa] = *reinterpret_cast<const float4*>(W + o * D + i);
        }

        if (tid < T)  sC[tid]  = 0.01f * __expf((float)(127 - tid) * LN_ETA_DECAY);
        if (tid < 64) sB0[tid] = bparam[obase + tid];

        // stage sErr (direct errW read) and sKs = 2*c[t]*keys[t, i-tile]
        #pragma unroll
        for (int p = 0; p < 8; ++p) {
            const int idx = tid + p * 256;
            const int t = idx >> 4, q = idx & 15;
            float4 ev = *reinterpret_cast<const float4*>(errW + t * D + obase + q * 4);
            *reinterpret_cast<float4*>(&sErr[t][q * 4]) = ev;

            const float c2 = 2.f * 0.01f * __expf((float)(127 - t) * LN_ETA_DECAY);
            float4 kv = *reinterpret_cast<const float4*>(keys + t * D + ibase + q * 4);
            kv.x *= c2; kv.y *= c2; kv.z *= c2; kv.w *= c2;
            *reinterpret_cast<float4*>(&sKs[t][q * 4]) = kv;
        }
        __syncthreads();

        float acc[4][4];
        #pragma unroll
        for (int a = 0; a < 4; ++a)
            #pragma unroll
            for (int n = 0; n < 4; ++n) acc[a][n] = 0.f;

        #pragma unroll 4
        for (int t = 0; t < T; ++t) {
            float4 a = *reinterpret_cast<const float4*>(&sErr[t][ty * 4]);
            float4 bb = *reinterpret_cast<const float4*>(&sKs[t][tx * 4]);
            const float av[4] = { a.x, a.y, a.z, a.w };
            const float bv[4] = { bb.x, bb.y, bb.z, bb.w };
            #pragma unroll
            for (int aa = 0; aa < 4; ++aa)
                #pragma unroll
                for (int nn = 0; nn < 4; ++nn) acc[aa][nn] += av[aa] * bv[nn];
        }

        // W / mW epilogue from prefetched regs
        #pragma unroll
        for (int aa = 0; aa < 4; ++aa) {
            const int o = obase + ty * 4 + aa;
            const int i = ibase + tx * 4;
            float4 nm, wn;
            nm.x = pow_eta_T * pm[aa].x - acc[aa][0];
            nm.y = pow_eta_T * pm[aa].y - acc[aa][1];
            nm.z = pow_eta_T * pm[aa].z - acc[aa][2];
            nm.w = pow_eta_T * pm[aa].w - acc[aa][3];
            wn.x = beta_total * pw[aa].x + nm.x;
            wn.y = beta_total * pw[aa].y + nm.y;
            wn.z = beta_total * pw[aa].z + nm.z;
            wn.w = beta_total * pw[aa].w + nm.w;
            *reinterpret_cast<float4*>(mW_new + o * D + i) = nm;
            *reinterpret_cast<float4*>(W_new + o * D + i) = wn;
        }

        // b epilogue (once per o-tile)
        if (iT == 0 && tid < 64) {
            float S = 0.f;
            for (int t = 0; t < T; ++t) S += sC[t] * sErr[t][tid];
            const int o = obase + tid;
            const float nmb = pow_eta_T * mb[o] - 2.f * S - 2.f * Csum * sB0[tid];
            mb_new[o] = nmb;
            b_new[o]  = beta_total * sB0[tid] + nmb;
        }

        // losses partial (once per o-tile)
        if (iT == 1) {
            const int t = tid >> 1, h = tid & 1;
            float L = 0.f;
            #pragma unroll 8
            for (int oo = 0; oo < 32; ++oo) {
                const int o = ((h * 32 + oo) + t) & 63;   // skew to dodge bank aliasing
                const float e = sErr[t][o] + sB0[o];
                L += e * e;
            }
            L += __shfl_xor(L, 1, 64);
            if (h == 0) atomicAdd(losses + t, L * (1.f / 768.f));
        }
    }
}

extern "C" void kernel_launch(void* const* d_in, const int* in_sizes, int n_in,
                              void* d_out, int out_size, void* d_ws, size_t ws_size,
                              hipStream_t stream) {
    const float* W      = (const float*)d_in[0];
    const float* bparam = (const float*)d_in[1];
    const float* keys   = (const float*)d_in[2];
    const float* values = (const float*)d_in[3];
    const float* mW     = (const float*)d_in[4];
    const float* mb     = (const float*)d_in[5];

    float* out = (float*)d_out;
    float* W_new  = out;               // 768*768
    float* b_new  = out + 589824;      // 768
    float* mW_new = out + 590592;      // 768*768
    float* mb_new = out + 1180416;     // 768
    float* losses = out + 1181184;     // 128

    float* Ppart = (float*)d_ws;                 // KC*T*D floats = 6.3 MB
    float* errW  = Ppart + KC * T * D;           // T*D floats

    double cs = 0.0;
    for (int t = 0; t < T; ++t) cs += 0.01 * pow(0.891, 127 - t);
    float pow_eta_T  = (float)pow(0.9, 128);
    float beta_total = (float)pow(0.99, 128);
    float Csum = (float)cs;

    void* args[] = {
        (void*)&W, (void*)&keys, (void*)&values, (void*)&mW,
        (void*)&bparam, (void*)&mb,
        (void*)&W_new, (void*)&b_new, (void*)&mW_new, (void*)&mb_new,
        (void*)&losses, (void*)&Ppart, (void*)&errW,
        (void*)&pow_eta_T, (void*)&beta_total, (void*)&Csum
    };
    hipLaunchCooperativeKernel((const void*)fused_all, dim3(192), dim3(256),
                               args, 0, stream);
}

// Round 2
// 84.072 us; speedup vs baseline: 1.7516x; 1.7516x over previous
//
#include <hip/hip_runtime.h>
#include <math.h>

#define D 768
#define T 128
#define KC 16            // split-K chunks for GEMM1
#define CHUNKK (D / KC)  // 48
#define NSUB (CHUNKK / 16) // 3 sub-chunks of 16

// ln(0.9*0.99) = ln(0.891)
#define LN_ETA_DECAY (-0.11541085151132775f)

// ---------------------------------------------------------------------------
// K1: split-K partial GEMM  P = keys @ W^T   (M=128 t, N=768 o, K=768)
// grid = (12 o-tiles, KC=16 k-chunks) = 192 blocks, 512 threads (8 waves/CU,
// 2/SIMD — doubles latency hiding vs the 256-thread variant at identical
// per-CU work). K-major LDS tiles + register double-buffered staging.
// Per-thread tile 4t x 4o. Block (0,0) zeroes losses (k2's atomic target).
// ---------------------------------------------------------------------------
__global__ __launch_bounds__(512) void k1_pgemm(
    const float* __restrict__ W,
    const float* __restrict__ keys,
    float* __restrict__ Ppart,
    float* __restrict__ losses)
{
    __shared__ float sKt[16][132];  // [k][t], pitch 132
    __shared__ float sWo[16][68];   // [k][o], pitch 68

    const int obase = blockIdx.x * 64;
    const int kbase = blockIdx.y * CHUNKK;
    const int tid = threadIdx.x;
    const int ty = tid >> 4;   // t-group (4 t's), 0..31
    const int tx = tid & 15;   // o-group (4 o's)
    const int t0 = tid >> 2;   // keys staging row (0..127)
    const int q0 = tid & 3;    // staging float4-col (0..3)
    const int o0 = (tid >> 2) & 63; // W staging row for tid<256

    if (blockIdx.x == 0 && blockIdx.y == 0 && tid < T) losses[tid] = 0.f;

    float acc[4][4];
    #pragma unroll
    for (int j = 0; j < 4; ++j)
        #pragma unroll
        for (int n = 0; n < 4; ++n) acc[j][n] = 0.f;

    // prologue: load sub-chunk 0 into regs
    float4 gk = *reinterpret_cast<const float4*>(keys + t0 * D + kbase + q0 * 4);
    float4 gw;
    if (tid < 256)
        gw = *reinterpret_cast<const float4*>(W + (obase + o0) * D + kbase + q0 * 4);

    for (int c = 0; c < NSUB; ++c) {
        // regs -> LDS (transposed to k-major)
        sKt[q0 * 4 + 0][t0] = gk.x;
        sKt[q0 * 4 + 1][t0] = gk.y;
        sKt[q0 * 4 + 2][t0] = gk.z;
        sKt[q0 * 4 + 3][t0] = gk.w;
        if (tid < 256) {
            sWo[q0 * 4 + 0][o0] = gw.x;
            sWo[q0 * 4 + 1][o0] = gw.y;
            sWo[q0 * 4 + 2][o0] = gw.z;
            sWo[q0 * 4 + 3][o0] = gw.w;
        }
        __syncthreads();

        // issue NEXT sub-chunk's loads (consumed at next iteration's store)
        if (c + 1 < NSUB) {
            const int kb = kbase + (c + 1) * 16;
            gk = *reinterpret_cast<const float4*>(keys + t0 * D + kb + q0 * 4);
            if (tid < 256)
                gw = *reinterpret_cast<const float4*>(W + (obase + o0) * D + kb + q0 * 4);
        }

        #pragma unroll
        for (int k = 0; k < 16; ++k) {
            float4 a = *reinterpret_cast<const float4*>(&sKt[k][ty * 4]);
            float4 b = *reinterpret_cast<const float4*>(&sWo[k][tx * 4]);
            const float av[4] = { a.x, a.y, a.z, a.w };
            const float bv[4] = { b.x, b.y, b.z, b.w };
            #pragma unroll
            for (int j = 0; j < 4; ++j)
                #pragma unroll
                for (int n = 0; n < 4; ++n) acc[j][n] += av[j] * bv[n];
        }
        __syncthreads();
    }

    float* outp = Ppart + blockIdx.y * (T * D);
    #pragma unroll
    for (int j = 0; j < 4; ++j) {
        const int t = ty * 4 + j;
        float4 v = { acc[j][0], acc[j][1], acc[j][2], acc[j][3] };
        *reinterpret_cast<float4*>(outp + t * D + obase + tx * 4) = v;
    }
}

// ---------------------------------------------------------------------------
// K1.5: errW[t][o] = sum_kc Ppart[kc][t][o] - values[t][o].
// 192 blocks x 256 threads, one float2 per thread (192*256*2 = 98304 = T*D),
// 16 independent partial loads in flight. Twice the CUs of the float4/96-block
// variant -> shorter per-CU latency chain.
// ---------------------------------------------------------------------------
__global__ __launch_bounds__(256) void k15_reduce(
    const float* __restrict__ Ppart,
    const float* __restrict__ values,
    float* __restrict__ errW)
{
    const int off = (blockIdx.x * 256 + threadIdx.x) * 2;
    float2 vv = *reinterpret_cast<const float2*>(values + off);
    float2 s = { -vv.x, -vv.y };
    #pragma unroll
    for (int kc = 0; kc < KC; ++kc) {
        float2 v = *reinterpret_cast<const float2*>(Ppart + kc * (T * D) + off);
        s.x += v.x; s.y += v.y;
    }
    *reinterpret_cast<float2*>(errW + off) = s;
}

// ---------------------------------------------------------------------------
// K2: GEMM2 G = errW^T @ (2c*keys) + fused W/mW epilogue (mW/W prefetched
// into regs so their HBM latency hides under staging+GEMM). iT==0 blocks
// emit b_new/mb_new; iT==1 blocks add loss partials (losses zeroed by k1).
// grid = 144 (12 oT x 12 iT), 256 threads.
// ---------------------------------------------------------------------------
__global__ __launch_bounds__(256) void k2_main(
    const float* __restrict__ errW,
    const float* __restrict__ keys,
    const float* __restrict__ W,
    const float* __restrict__ mW,
    const float* __restrict__ bparam,
    const float* __restrict__ mb,
    float* __restrict__ W_new,
    float* __restrict__ b_new,
    float* __restrict__ mW_new,
    float* __restrict__ mb_new,
    float* __restrict__ losses,
    float pow_eta_T, float beta_total, float Csum)
{
    __shared__ float sErr[T][64];   // errW[t, o-local]
    __shared__ float sKs[T][64];    // 2*c[t]*keys[t, i-local]
    __shared__ float sC[T];         // c[t]
    __shared__ float sB0[64];       // bparam[o-local]

    const int oT = blockIdx.x / 12, iT = blockIdx.x % 12;
    const int obase = oT * 64, ibase = iT * 64;
    const int tid = threadIdx.x;
    const int ty = tid >> 4, tx = tid & 15;   // o-group, i-group

    // ---- epilogue prefetch: issue mW/W loads NOW, consume after GEMM2 ----
    float4 pm[4], pw[4];
    #pragma unroll
    for (int aa = 0; aa < 4; ++aa) {
        const int o = obase + ty * 4 + aa;
        const int i = ibase + tx * 4;
        pm[aa] = *reinterpret_cast<const float4*>(mW + o * D + i);
        pw[aa] = *reinterpret_cast<const float4*>(W + o * D + i);
    }

    if (tid < T)  sC[tid]  = 0.01f * __expf((float)(127 - tid) * LN_ETA_DECAY);
    if (tid < 64) sB0[tid] = bparam[obase + tid];

    // stage sErr (direct errW read) and sKs = 2*c[t]*keys[t, i-tile]
    #pragma unroll
    for (int p = 0; p < 8; ++p) {
        const int idx = tid + p * 256;
        const int t = idx >> 4, q = idx & 15;
        float4 ev = *reinterpret_cast<const float4*>(errW + t * D + obase + q * 4);
        *reinterpret_cast<float4*>(&sErr[t][q * 4]) = ev;

        const float c2 = 2.f * 0.01f * __expf((float)(127 - t) * LN_ETA_DECAY);
        float4 kv = *reinterpret_cast<const float4*>(keys + t * D + ibase + q * 4);
        kv.x *= c2; kv.y *= c2; kv.z *= c2; kv.w *= c2;
        *reinterpret_cast<float4*>(&sKs[t][q * 4]) = kv;
    }
    __syncthreads();

    float acc[4][4];
    #pragma unroll
    for (int a = 0; a < 4; ++a)
        #pragma unroll
        for (int b = 0; b < 4; ++b) acc[a][b] = 0.f;

    #pragma unroll 4
    for (int t = 0; t < T; ++t) {
        float4 a = *reinterpret_cast<const float4*>(&sErr[t][ty * 4]);
        float4 b = *reinterpret_cast<const float4*>(&sKs[t][tx * 4]);
        const float av[4] = { a.x, a.y, a.z, a.w };
        const float bv[4] = { b.x, b.y, b.z, b.w };
        #pragma unroll
        for (int aa = 0; aa < 4; ++aa)
            #pragma unroll
            for (int bb = 0; bb < 4; ++bb) acc[aa][bb] += av[aa] * bv[bb];
    }

    // W / mW epilogue from prefetched regs
    #pragma unroll
    for (int aa = 0; aa < 4; ++aa) {
        const int o = obase + ty * 4 + aa;
        const int i = ibase + tx * 4;
        float4 nm, wn;
        nm.x = pow_eta_T * pm[aa].x - acc[aa][0];
        nm.y = pow_eta_T * pm[aa].y - acc[aa][1];
        nm.z = pow_eta_T * pm[aa].z - acc[aa][2];
        nm.w = pow_eta_T * pm[aa].w - acc[aa][3];
        wn.x = beta_total * pw[aa].x + nm.x;
        wn.y = beta_total * pw[aa].y + nm.y;
        wn.z = beta_total * pw[aa].z + nm.z;
        wn.w = beta_total * pw[aa].w + nm.w;
        *reinterpret_cast<float4*>(mW_new + o * D + i) = nm;
        *reinterpret_cast<float4*>(W_new + o * D + i) = wn;
    }

    // b epilogue (once per o-tile)
    if (iT == 0 && tid < 64) {
        float S = 0.f;
        for (int t = 0; t < T; ++t) S += sC[t] * sErr[t][tid];
        const int o = obase + tid;
        const float nmb = pow_eta_T * mb[o] - 2.f * S - 2.f * Csum * sB0[tid];
        mb_new[o] = nmb;
        b_new[o]  = beta_total * sB0[tid] + nmb;
    }

    // losses partial (once per o-tile)
    if (iT == 1) {
        const int t = tid >> 1, h = tid & 1;
        float L = 0.f;
        #pragma unroll 8
        for (int oo = 0; oo < 32; ++oo) {
            const int o = ((h * 32 + oo) + t) & 63;   // skew to dodge bank aliasing
            const float e = sErr[t][o] + sB0[o];
            L += e * e;
        }
        L += __shfl_xor(L, 1, 64);
        if (h == 0) atomicAdd(losses + t, L * (1.f / 768.f));
    }
}

extern "C" void kernel_launch(void* const* d_in, const int* in_sizes, int n_in,
                              void* d_out, int out_size, void* d_ws, size_t ws_size,
                              hipStream_t stream) {
    const float* W      = (const float*)d_in[0];
    const float* bparam = (const float*)d_in[1];
    const float* keys   = (const float*)d_in[2];
    const float* values = (const float*)d_in[3];
    const float* mW     = (const float*)d_in[4];
    const float* mb     = (const float*)d_in[5];

    float* out = (float*)d_out;
    float* W_new  = out;               // 768*768
    float* b_new  = out + 589824;      // 768
    float* mW_new = out + 590592;      // 768*768
    float* mb_new = out + 1180416;     // 768
    float* losses = out + 1181184;     // 128

    float* Ppart = (float*)d_ws;                 // KC*T*D floats = 6.3 MB
    float* errW  = Ppart + KC * T * D;           // T*D floats

    double cs = 0.0;
    for (int t = 0; t < T; ++t) cs += 0.01 * pow(0.891, 127 - t);
    const float pow_eta_T  = (float)pow(0.9, 128);
    const float beta_total = (float)pow(0.99, 128);
    const float Csum = (float)cs;

    k1_pgemm<<<dim3(12, KC), 512, 0, stream>>>(W, keys, Ppart, losses);
    k15_reduce<<<192, 256, 0, stream>>>(Ppart, values, errW);
    k2_main<<<144, 256, 0, stream>>>(errW, keys, W, mW, bparam, mb,
                                     W_new, b_new, mW_new, mb_new, losses,
                                     pow_eta_T, beta_total, Csum);
}